// Round 4
// baseline (209.569 us; speedup 1.0000x reference)
//
#include <hip/hip_runtime.h>

#define L_SEQ 4096
#define DMODEL 256
#define DH 64
#define NKB 16   // key blocks (of 64) per workgroup: 4096 / 64 / ksplit(4)

typedef __attribute__((ext_vector_type(8))) __bf16 bf16x8;
typedef __attribute__((ext_vector_type(4))) float f32x4;
typedef __attribute__((ext_vector_type(8))) unsigned short ushort8v;
typedef __attribute__((ext_vector_type(4))) unsigned short ushort4v;

__device__ __forceinline__ unsigned short f2bf(float f) {
  unsigned u = __builtin_bit_cast(unsigned, f);
  u += 0x7fffu + ((u >> 16) & 1u);
  return (unsigned short)(u >> 16);
}
__device__ __forceinline__ float bf2f(unsigned short h) {
  unsigned u = ((unsigned)h) << 16;
  return __builtin_bit_cast(float, u);
}
__device__ __forceinline__ bf16x8 ld_frag(const unsigned short* p) {
  return __builtin_bit_cast(bf16x8, *(const ushort8v*)p);
}

// ---- 1. q [B,C,L] fp32 -> xbf [B*L, C] bf16; blocks >=512 convert weights ----
__global__ __launch_bounds__(256) void k_transpose(const float* __restrict__ q,
                                                   unsigned short* __restrict__ xbf,
                                                   const float* __restrict__ w,
                                                   const float* __restrict__ fcw,
                                                   unsigned short* __restrict__ wbf,
                                                   unsigned short* __restrict__ fcwbf) {
  int bx = blockIdx.x;
  int t = threadIdx.x;
  if (bx >= 512) {   // weight conversion tail
    int i = ((bx - 512) * 256 + t) * 4;
    float4 a = *(const float4*)(w + i);
    float4 b = *(const float4*)(fcw + i);
    ushort4v av = {f2bf(a.x), f2bf(a.y), f2bf(a.z), f2bf(a.w)};
    ushort4v bv = {f2bf(b.x), f2bf(b.y), f2bf(b.z), f2bf(b.w)};
    *(ushort4v*)(wbf + i) = av;
    *(ushort4v*)(fcwbf + i) = bv;
    return;
  }
  __shared__ float T[64 * 65];
  int b = bx >> 8, rest = bx & 255;
  int ct = rest >> 6, lt = rest & 63;
#pragma unroll
  for (int it = 0; it < 4; ++it) {
    int i = (t >> 4) + it * 16;
    int j0 = (t & 15) * 4;
    float4 v = *(const float4*)(q + ((size_t)(b * 256 + ct * 64 + i)) * 4096 + lt * 64 + j0);
    T[i * 65 + j0 + 0] = v.x;
    T[i * 65 + j0 + 1] = v.y;
    T[i * 65 + j0 + 2] = v.z;
    T[i * 65 + j0 + 3] = v.w;
  }
  __syncthreads();
#pragma unroll
  for (int it = 0; it < 2; ++it) {
    int l = (t >> 3) + it * 32;
    int c0 = (t & 7) * 8;
    ushort8v o;
#pragma unroll
    for (int k = 0; k < 8; ++k) o[k] = f2bf(T[(c0 + k) * 65 + l]);
    *(ushort8v*)(xbf + ((size_t)(b * 4096 + lt * 64 + l)) * 256 + ct * 64 + c0) = o;
  }
}

// ---- 2. QKV GEMM -> Qh [p][l][d] and QhT [p][d][l] (LDS-bounced stores) ----
#define KP2 136
__global__ __launch_bounds__(256) void k_qkv(const unsigned short* __restrict__ xbf,
                                             const unsigned short* __restrict__ wbf,
                                             unsigned short* __restrict__ Qh,
                                             unsigned short* __restrict__ QhT) {
  __shared__ unsigned short As[64 * KP2];
  __shared__ unsigned short Bs[64 * KP2];
  int bx = blockIdx.x;
  int mtile = bx >> 2, h = bx & 3;
  int m0 = mtile * 64;
  int b = m0 >> 12, l0 = m0 & 4095;
  int t = threadIdx.x;
  int wv = t >> 6, lane = t & 63, g = lane >> 4, ln = lane & 15;
  f32x4 acc[4] = {};
  for (int kb = 0; kb < 2; ++kb) {
#pragma unroll
    for (int it = 0; it < 4; ++it) {
      int idx = t + it * 256;
      int row = idx >> 4;
      int c0 = (idx & 15) * 8;
      *(ushort8v*)(As + row * KP2 + c0) =
          *(const ushort8v*)(xbf + (size_t)(m0 + row) * 256 + kb * 128 + c0);
      *(ushort8v*)(Bs + row * KP2 + c0) =
          *(const ushort8v*)(wbf + (size_t)(h * 64 + row) * 256 + kb * 128 + c0);
    }
    __syncthreads();
#pragma unroll
    for (int kc = 0; kc < 4; ++kc) {
      bf16x8 a = ld_frag(As + (wv * 16 + ln) * KP2 + kc * 32 + g * 8);
#pragma unroll
      for (int tn = 0; tn < 4; ++tn) {
        bf16x8 bb = ld_frag(Bs + (tn * 16 + ln) * KP2 + kc * 32 + g * 8);
        acc[tn] = __builtin_amdgcn_mfma_f32_16x16x32_bf16(a, bb, acc[tn], 0, 0, 0);
      }
    }
    __syncthreads();
  }
  size_t pbase = (size_t)(b * 4 + h);
  // ---- epilogue: bounce tiles through LDS, then dense 16-B stores ----
  // As <- [l_local][d] tile (wave-private rows), Bs <- [d][l_local] tile
#pragma unroll
  for (int tn = 0; tn < 4; ++tn) {
#pragma unroll
    for (int r = 0; r < 4; ++r) {
      int lrow = wv * 16 + g * 4 + r;
      int d = tn * 16 + ln;
      unsigned short bv = f2bf(acc[tn][r]);
      As[lrow * 64 + (((d >> 3) ^ (lrow & 7)) * 8) + (d & 7)] = bv;
      Bs[d * 64 + (((lrow >> 3) ^ (d & 7)) * 8) + (lrow & 7)] = bv;
    }
  }
  // Qh: each wave stores its own 16 rows (no barrier; rows wave-private)
#pragma unroll
  for (int s = 0; s < 2; ++s) {
    int flat = s * 64 + lane;
    int lrow = wv * 16 + (flat >> 3);
    int c8 = lane & 7;
    ushort8v v = *(const ushort8v*)(As + lrow * 64 + ((c8 ^ (lrow & 7)) * 8));
    *(ushort8v*)(Qh + (pbase * L_SEQ + l0 + lrow) * DH + c8 * 8) = v;
  }
  __syncthreads();   // Bs rows are cross-wave
#pragma unroll
  for (int s = 0; s < 2; ++s) {
    int flat = s * 256 + t;
    int drow = flat >> 3;
    int c8 = t & 7;
    ushort8v v = *(const ushort8v*)(Bs + drow * 64 + ((c8 ^ (drow & 7)) * 8));
    *(ushort8v*)(QhT + (pbase * DH + drow) * L_SEQ + l0 + c8 * 8) = v;
  }
}

// ---- 3. flash attention, S^T = K Q^T form, fixed-max softmax, key-split 4 ----
// grid 512: p = bx&7 (XCD), qsup = (bx>>3)&15 (256 q rows), ks = bx>>7 (0..3)
// Partial O (bf16) and L (fp32) per ks partition — dense coalesced stores.
__global__ __launch_bounds__(256, 3) void k_attn(const unsigned short* __restrict__ Qh,
                                                 const unsigned short* __restrict__ QhT,
                                                 unsigned short* __restrict__ Opart,
                                                 float* __restrict__ Lpart) {
  __shared__ unsigned short Kt[64 * 64];   // [key][d], 16B chunks XOR-swizzled by row&7
  __shared__ unsigned short Vt[64 * 64];   // [d][key], same swizzle
  __shared__ unsigned short Pb[256 * 64];  // [q_local][key], same swizzle, wave-private rows
  int bx = blockIdx.x;
  int p = bx & 7;
  int u = bx >> 3;
  int qsup = u & 15, ks = u >> 4;
  int t = threadIdx.x;
  int wv = t >> 6, lane = t & 63, g = lane >> 4, ln = lane & 15;
  const unsigned short* Qp = Qh + (size_t)p * L_SEQ * DH;
  const unsigned short* QTp = QhT + (size_t)p * DH * L_SEQ;
  int q0 = qsup * 256;
  int qw = q0 + wv * 64;  // this wave's 64 q-columns

  // Q^T fragments (B operand), cached for the whole loop: 8 x b128
  bf16x8 aQ[4][2];
#pragma unroll
  for (int nt = 0; nt < 4; ++nt)
#pragma unroll
    for (int kc = 0; kc < 2; ++kc)
      aQ[nt][kc] = ld_frag(Qp + (size_t)(qw + nt * 16 + ln) * DH + kc * 32 + g * 8);

  f32x4 oacc[4][4] = {};
  float lacc[4] = {0.f, 0.f, 0.f, 0.f};

  // staging addresses (2 chunks each of Kt, Vt per thread)
  int srow0 = t >> 3, scol0 = t & 7;
  int srow1 = (t + 256) >> 3, scol1 = (t + 256) & 7;
  int sdst0 = srow0 * 64 + ((scol0 ^ (srow0 & 7)) * 8);
  int sdst1 = srow1 * 64 + ((scol1 ^ (srow1 & 7)) * 8);

  ushort8v kreg0, kreg1, vreg0, vreg1;
  {
    int kbase = (ks * NKB) * 64;
    kreg0 = *(const ushort8v*)(Qp + (size_t)(kbase + srow0) * DH + scol0 * 8);
    kreg1 = *(const ushort8v*)(Qp + (size_t)(kbase + srow1) * DH + scol1 * 8);
    vreg0 = *(const ushort8v*)(QTp + (size_t)srow0 * L_SEQ + kbase + scol0 * 8);
    vreg1 = *(const ushort8v*)(QTp + (size_t)srow1 * L_SEQ + kbase + scol1 * 8);
  }

  for (int kb = 0; kb < NKB; ++kb) {
    __syncthreads();  // all waves done reading Kt/Vt of previous kb
    *(ushort8v*)(Kt + sdst0) = kreg0;
    *(ushort8v*)(Kt + sdst1) = kreg1;
    *(ushort8v*)(Vt + sdst0) = vreg0;
    *(ushort8v*)(Vt + sdst1) = vreg1;
    __syncthreads();  // staging visible
    if (kb + 1 < NKB) {
      int kbase = (ks * NKB + kb + 1) * 64;
      kreg0 = *(const ushort8v*)(Qp + (size_t)(kbase + srow0) * DH + scol0 * 8);
      kreg1 = *(const ushort8v*)(Qp + (size_t)(kbase + srow1) * DH + scol1 * 8);
      vreg0 = *(const ushort8v*)(QTp + (size_t)srow0 * L_SEQ + kbase + scol0 * 8);
      vreg1 = *(const ushort8v*)(QTp + (size_t)srow1 * L_SEQ + kbase + scol1 * 8);
    }
    // ---- S^T = K Q^T, one 16-key m-tile at a time ----
#pragma unroll
    for (int mt = 0; mt < 4; ++mt) {
      int krow = mt * 16 + ln;
      bf16x8 aK0 = ld_frag(Kt + krow * 64 + (((0 * 4 + g) ^ (ln & 7)) * 8));
      bf16x8 aK1 = ld_frag(Kt + krow * 64 + (((1 * 4 + g) ^ (ln & 7)) * 8));
      f32x4 s[4] = {};
#pragma unroll
      for (int nt = 0; nt < 4; ++nt) {
        s[nt] = __builtin_amdgcn_mfma_f32_16x16x32_bf16(aK0, aQ[nt][0], s[nt], 0, 0, 0);
        s[nt] = __builtin_amdgcn_mfma_f32_16x16x32_bf16(aK1, aQ[nt][1], s[nt], 0, 0, 0);
      }
      // exp(s/8 - 16), accumulate l, pack P^T tile rows -> Pb[q][key] (b64 writes)
#pragma unroll
      for (int nt = 0; nt < 4; ++nt) {
        float p0 = __expf(fmaf(s[nt][0], 0.125f, -16.0f));
        float p1 = __expf(fmaf(s[nt][1], 0.125f, -16.0f));
        float p2 = __expf(fmaf(s[nt][2], 0.125f, -16.0f));
        float p3 = __expf(fmaf(s[nt][3], 0.125f, -16.0f));
        lacc[nt] += (p0 + p1) + (p2 + p3);
        ushort4v pk = {f2bf(p0), f2bf(p1), f2bf(p2), f2bf(p3)};
        int row = wv * 64 + nt * 16 + ln;
        int addr = row * 64 + (((2 * mt + (g >> 1)) ^ (ln & 7)) * 8) + (g & 1) * 4;
        *(ushort4v*)(Pb + addr) = pk;
      }
    }
    // ---- O += P V ----
#pragma unroll
    for (int kc = 0; kc < 2; ++kc) {
      bf16x8 bV[4];
#pragma unroll
      for (int tn = 0; tn < 4; ++tn)
        bV[tn] = ld_frag(Vt + (tn * 16 + ln) * 64 + (((kc * 4 + g) ^ (ln & 7)) * 8));
#pragma unroll
      for (int mq = 0; mq < 4; ++mq) {
        bf16x8 aP = ld_frag(Pb + (wv * 64 + mq * 16 + ln) * 64 + (((kc * 4 + g) ^ (ln & 7)) * 8));
#pragma unroll
        for (int tn = 0; tn < 4; ++tn)
          oacc[mq][tn] = __builtin_amdgcn_mfma_f32_16x16x32_bf16(aP, bV[tn], oacc[mq][tn], 0, 0, 0);
      }
    }
  }
  // l: reduce over the 4 g-quads
#pragma unroll
  for (int nt = 0; nt < 4; ++nt) {
    lacc[nt] += __shfl_xor(lacc[nt], 16, 64);
    lacc[nt] += __shfl_xor(lacc[nt], 32, 64);
  }
  size_t pq = (size_t)(ks * 8 + p) * L_SEQ;
  if (g == 0) {
#pragma unroll
    for (int nt = 0; nt < 4; ++nt)
      Lpart[pq + qw + nt * 16 + ln] = lacc[nt];
  }
  // ---- epilogue: bounce O through Pb (wave-private rows), dense 16-B stores ----
#pragma unroll
  for (int mq = 0; mq < 4; ++mq) {
#pragma unroll
    for (int r = 0; r < 4; ++r) {
      int row = wv * 64 + mq * 16 + g * 4 + r;   // q_local in [wv*64, wv*64+64)
#pragma unroll
      for (int tn = 0; tn < 4; ++tn) {
        int d = tn * 16 + ln;
        Pb[row * 64 + (((d >> 3) ^ (row & 7)) * 8) + (d & 7)] = f2bf(oacc[mq][tn][r]);
      }
    }
  }
  // no barrier needed: each wave reads back only its own rows
#pragma unroll
  for (int s = 0; s < 8; ++s) {
    int flat = s * 64 + lane;
    int row = wv * 64 + (flat >> 3);
    int c8 = lane & 7;
    ushort8v v = *(const ushort8v*)(Pb + row * 64 + ((c8 ^ (row & 7)) * 8));
    *(ushort8v*)(Opart + (pq + q0 + row) * DH + c8 * 8) = v;
  }
}

// ---- 4. FC GEMM (fused ks-merge in A-staging) + bias + residual + LayerNorm ----
#define CP 72
__global__ __launch_bounds__(256) void k_fc(const unsigned short* __restrict__ Opart,
                                            const float* __restrict__ Lpart,
                                            const unsigned short* __restrict__ fcwbf,
                                            const float* __restrict__ qres,
                                            const float* __restrict__ fcb,
                                            const float* __restrict__ lng,
                                            const float* __restrict__ lnb,
                                            float* __restrict__ out) {
  __shared__ unsigned short As[32 * CP];
  __shared__ unsigned short Bs[256 * CP];
  __shared__ float redS[4][32], redQ[4][32], muA[32], rsA[32];
  int bx = blockIdx.x;
  int m0 = bx * 32;
  int b = m0 >> 12, lpart = m0 & 4095;
  int t = threadIdx.x;
  int wv = t >> 6, lane = t & 63, g = lane >> 4, ln = lane & 15;
  f32x4 acc[2][4] = {};
  for (int kb = 0; kb < 4; ++kb) {   // kb == head index for A-staging
    {
      int row = t >> 3, c0 = (t & 7) * 8;
      int q = lpart + row;
      int p = b * 4 + kb;
      float lsum = Lpart[(size_t)(0 * 8 + p) * L_SEQ + q] + Lpart[(size_t)(1 * 8 + p) * L_SEQ + q] +
                   Lpart[(size_t)(2 * 8 + p) * L_SEQ + q] + Lpart[(size_t)(3 * 8 + p) * L_SEQ + q];
      float inv = 1.0f / lsum;
      float a8[8] = {0.f, 0.f, 0.f, 0.f, 0.f, 0.f, 0.f, 0.f};
#pragma unroll
      for (int ksp = 0; ksp < 4; ++ksp) {
        ushort8v v = *(const ushort8v*)(Opart + ((size_t)(ksp * 8 + p) * L_SEQ + q) * DH + c0);
#pragma unroll
        for (int j = 0; j < 8; ++j) a8[j] += bf2f(v[j]);
      }
      ushort8v o;
#pragma unroll
      for (int j = 0; j < 8; ++j) o[j] = f2bf(a8[j] * inv);
      *(ushort8v*)(As + row * CP + c0) = o;
    }
#pragma unroll
    for (int it = 0; it < 8; ++it) {
      int idx = t + it * 256;
      int row = idx >> 3, c0 = (idx & 7) * 8;
      *(ushort8v*)(Bs + row * CP + c0) =
          *(const ushort8v*)(fcwbf + (size_t)row * 256 + kb * 64 + c0);
    }
    __syncthreads();
#pragma unroll
    for (int kc = 0; kc < 2; ++kc) {
      bf16x8 a[2], bb[4];
#pragma unroll
      for (int mt = 0; mt < 2; ++mt) a[mt] = ld_frag(As + (mt * 16 + ln) * CP + kc * 32 + g * 8);
#pragma unroll
      for (int tn = 0; tn < 4; ++tn) bb[tn] = ld_frag(Bs + (wv * 64 + tn * 16 + ln) * CP + kc * 32 + g * 8);
#pragma unroll
      for (int mt = 0; mt < 2; ++mt)
#pragma unroll
        for (int tn = 0; tn < 4; ++tn)
          acc[mt][tn] = __builtin_amdgcn_mfma_f32_16x16x32_bf16(a[mt], bb[tn], acc[mt][tn], 0, 0, 0);
    }
    __syncthreads();
  }
  float fb[4], lg[4], lb[4];
#pragma unroll
  for (int tn = 0; tn < 4; ++tn) {
    int o = wv * 64 + tn * 16 + ln;
    fb[tn] = fcb[o]; lg[tn] = lng[o]; lb[tn] = lnb[o];
  }
#pragma unroll
  for (int mt = 0; mt < 2; ++mt) {
    float ps[4] = {0.f, 0.f, 0.f, 0.f}, pq2[4] = {0.f, 0.f, 0.f, 0.f};
#pragma unroll
    for (int tn = 0; tn < 4; ++tn) {
      int o = wv * 64 + tn * 16 + ln;
      float4 res = *(const float4*)(qres + ((size_t)(b * 256 + o)) * 4096 + lpart + mt * 16 + g * 4);
      float rv[4] = {res.x, res.y, res.z, res.w};
#pragma unroll
      for (int r = 0; r < 4; ++r) {
        float v = acc[mt][tn][r] + fb[tn] + rv[r];
        acc[mt][tn][r] = v;
        ps[r] += v;
        pq2[r] += v * v;
      }
    }
#pragma unroll
    for (int r = 0; r < 4; ++r) {
      float s = ps[r], q2 = pq2[r];
#pragma unroll
      for (int off = 1; off < 16; off <<= 1) {
        s += __shfl_xor(s, off, 64);
        q2 += __shfl_xor(q2, off, 64);
      }
      if (ln == 0) {
        int row = mt * 16 + g * 4 + r;
        redS[wv][row] = s;
        redQ[wv][row] = q2;
      }
    }
  }
  __syncthreads();
  if (t < 32) {
    float s = redS[0][t] + redS[1][t] + redS[2][t] + redS[3][t];
    float q2 = redQ[0][t] + redQ[1][t] + redQ[2][t] + redQ[3][t];
    float mu = s * (1.f / 256.f);
    float var = q2 * (1.f / 256.f) - mu * mu;
    muA[t] = mu;
    rsA[t] = rsqrtf(var + 1e-5f);
  }
  __syncthreads();
#pragma unroll
  for (int mt = 0; mt < 2; ++mt) {
#pragma unroll
    for (int r = 0; r < 4; ++r) {
      int row = mt * 16 + g * 4 + r;
      float mu = muA[row], rs = rsA[row];
#pragma unroll
      for (int tn = 0; tn < 4; ++tn) {
        int o = wv * 64 + tn * 16 + ln;
        out[(size_t)(m0 + row) * 256 + o] = (acc[mt][tn][r] - mu) * rs * lg[tn] + lb[tn];
      }
    }
  }
}

extern "C" void kernel_launch(void* const* d_in, const int* in_sizes, int n_in,
                              void* d_out, int out_size, void* d_ws, size_t ws_size,
                              hipStream_t stream) {
  const float* q = (const float*)d_in[0];
  const float* w_qkv = (const float*)d_in[1];
  const float* fc_w = (const float*)d_in[2];
  const float* fc_b = (const float*)d_in[3];
  const float* ln_g = (const float*)d_in[4];
  const float* ln_b = (const float*)d_in[5];
  float* out = (float*)d_out;

  unsigned short* wbf = (unsigned short*)d_ws;   // 65536
  unsigned short* fcwbf = wbf + 65536;           // 65536
  unsigned short* xbf = fcwbf + 65536;           // 8192*256
  unsigned short* Qh = xbf + 2097152;            // [p][l][d]
  unsigned short* QhT = Qh + 2097152;            // [p][d][l]
  unsigned short* Opart = QhT + 2097152;         // [ks][p][q][d] bf16, 4*2M
  float* Lpart = (float*)(Opart + 8388608);      // [ks][p][q] fp32
  // total ws use: ~30.1 MB

  k_transpose<<<dim3(576), dim3(256), 0, stream>>>(q, xbf, w_qkv, fc_w, wbf, fcwbf);
  k_qkv<<<dim3(512), dim3(256), 0, stream>>>(xbf, wbf, Qh, QhT);
  k_attn<<<dim3(512), dim3(256), 0, stream>>>(Qh, QhT, Opart, Lpart);
  k_fc<<<dim3(256), dim3(256), 0, stream>>>(Opart, Lpart, fcwbf, q, fc_b, ln_g, ln_b, out);
}

// Round 5
// 139.339 us; speedup vs baseline: 1.5040x; 1.5040x over previous
//
#include <hip/hip_runtime.h>

#define L_SEQ 4096
#define DMODEL 256
#define DH 64
#define NKB 16   // key blocks (of 64) per workgroup: 4096 / 64 / ksplit(4)

typedef __attribute__((ext_vector_type(8))) __bf16 bf16x8;
typedef __attribute__((ext_vector_type(4))) float f32x4;
typedef __attribute__((ext_vector_type(8))) unsigned short ushort8v;
typedef __attribute__((ext_vector_type(4))) unsigned short ushort4v;

__device__ __forceinline__ unsigned short f2bf(float f) {
  unsigned u = __builtin_bit_cast(unsigned, f);
  u += 0x7fffu + ((u >> 16) & 1u);
  return (unsigned short)(u >> 16);
}
__device__ __forceinline__ float bf2f(unsigned short h) {
  unsigned u = ((unsigned)h) << 16;
  return __builtin_bit_cast(float, u);
}
__device__ __forceinline__ bf16x8 ld_frag(const unsigned short* p) {
  return __builtin_bit_cast(bf16x8, *(const ushort8v*)p);
}

// ---- 1. q [B,C,L] fp32 -> xbf [B*L, C] bf16; blocks >=512 convert weights ----
__global__ __launch_bounds__(256) void k_transpose(const float* __restrict__ q,
                                                   unsigned short* __restrict__ xbf,
                                                   const float* __restrict__ w,
                                                   const float* __restrict__ fcw,
                                                   unsigned short* __restrict__ wbf,
                                                   unsigned short* __restrict__ fcwbf) {
  int bx = blockIdx.x;
  int t = threadIdx.x;
  if (bx >= 512) {   // weight conversion tail
    int i = ((bx - 512) * 256 + t) * 4;
    float4 a = *(const float4*)(w + i);
    float4 b = *(const float4*)(fcw + i);
    ushort4v av = {f2bf(a.x), f2bf(a.y), f2bf(a.z), f2bf(a.w)};
    ushort4v bv = {f2bf(b.x), f2bf(b.y), f2bf(b.z), f2bf(b.w)};
    *(ushort4v*)(wbf + i) = av;
    *(ushort4v*)(fcwbf + i) = bv;
    return;
  }
  __shared__ float T[64 * 65];
  int b = bx >> 8, rest = bx & 255;
  int ct = rest >> 6, lt = rest & 63;
#pragma unroll
  for (int it = 0; it < 4; ++it) {
    int i = (t >> 4) + it * 16;
    int j0 = (t & 15) * 4;
    float4 v = *(const float4*)(q + ((size_t)(b * 256 + ct * 64 + i)) * 4096 + lt * 64 + j0);
    T[i * 65 + j0 + 0] = v.x;
    T[i * 65 + j0 + 1] = v.y;
    T[i * 65 + j0 + 2] = v.z;
    T[i * 65 + j0 + 3] = v.w;
  }
  __syncthreads();
#pragma unroll
  for (int it = 0; it < 2; ++it) {
    int l = (t >> 3) + it * 32;
    int c0 = (t & 7) * 8;
    ushort8v o;
#pragma unroll
    for (int k = 0; k < 8; ++k) o[k] = f2bf(T[(c0 + k) * 65 + l]);
    *(ushort8v*)(xbf + ((size_t)(b * 4096 + lt * 64 + l)) * 256 + ct * 64 + c0) = o;
  }
}

// ---- 2. QKV GEMM -> Qh [p][l][d] and QhT [p][d][l] (LDS-bounced stores) ----
#define KP2 136
__global__ __launch_bounds__(256) void k_qkv(const unsigned short* __restrict__ xbf,
                                             const unsigned short* __restrict__ wbf,
                                             unsigned short* __restrict__ Qh,
                                             unsigned short* __restrict__ QhT) {
  __shared__ unsigned short As[64 * KP2];
  __shared__ unsigned short Bs[64 * KP2];
  int bx = blockIdx.x;
  int mtile = bx >> 2, h = bx & 3;
  int m0 = mtile * 64;
  int b = m0 >> 12, l0 = m0 & 4095;
  int t = threadIdx.x;
  int wv = t >> 6, lane = t & 63, g = lane >> 4, ln = lane & 15;
  f32x4 acc[4] = {};
  for (int kb = 0; kb < 2; ++kb) {
#pragma unroll
    for (int it = 0; it < 4; ++it) {
      int idx = t + it * 256;
      int row = idx >> 4;
      int c0 = (idx & 15) * 8;
      *(ushort8v*)(As + row * KP2 + c0) =
          *(const ushort8v*)(xbf + (size_t)(m0 + row) * 256 + kb * 128 + c0);
      *(ushort8v*)(Bs + row * KP2 + c0) =
          *(const ushort8v*)(wbf + (size_t)(h * 64 + row) * 256 + kb * 128 + c0);
    }
    __syncthreads();
#pragma unroll
    for (int kc = 0; kc < 4; ++kc) {
      bf16x8 a = ld_frag(As + (wv * 16 + ln) * KP2 + kc * 32 + g * 8);
#pragma unroll
      for (int tn = 0; tn < 4; ++tn) {
        bf16x8 bb = ld_frag(Bs + (tn * 16 + ln) * KP2 + kc * 32 + g * 8);
        acc[tn] = __builtin_amdgcn_mfma_f32_16x16x32_bf16(a, bb, acc[tn], 0, 0, 0);
      }
    }
    __syncthreads();
  }
  size_t pbase = (size_t)(b * 4 + h);
  // ---- epilogue: bounce tiles through LDS, then dense 16-B stores ----
  // As <- [l_local][d] tile (wave-private rows), Bs <- [d][l_local] tile
#pragma unroll
  for (int tn = 0; tn < 4; ++tn) {
#pragma unroll
    for (int r = 0; r < 4; ++r) {
      int lrow = wv * 16 + g * 4 + r;
      int d = tn * 16 + ln;
      unsigned short bv = f2bf(acc[tn][r]);
      As[lrow * 64 + (((d >> 3) ^ (lrow & 7)) * 8) + (d & 7)] = bv;
      Bs[d * 64 + (((lrow >> 3) ^ (d & 7)) * 8) + (lrow & 7)] = bv;
    }
  }
  // Qh: each wave stores its own 16 rows (no barrier; rows wave-private)
#pragma unroll
  for (int s = 0; s < 2; ++s) {
    int flat = s * 64 + lane;
    int lrow = wv * 16 + (flat >> 3);
    int c8 = lane & 7;
    ushort8v v = *(const ushort8v*)(As + lrow * 64 + ((c8 ^ (lrow & 7)) * 8));
    *(ushort8v*)(Qh + (pbase * L_SEQ + l0 + lrow) * DH + c8 * 8) = v;
  }
  __syncthreads();   // Bs rows are cross-wave
#pragma unroll
  for (int s = 0; s < 2; ++s) {
    int flat = s * 256 + t;
    int drow = flat >> 3;
    int c8 = t & 7;
    ushort8v v = *(const ushort8v*)(Bs + drow * 64 + ((c8 ^ (drow & 7)) * 8));
    *(ushort8v*)(QhT + (pbase * DH + drow) * L_SEQ + l0 + c8 * 8) = v;
  }
}

// ---- 3. flash attention, S^T = K Q^T form, fixed-max softmax, key-split 4 ----
// grid 512: p = bx&7 (XCD), qsup = (bx>>3)&15 (256 q rows), ks = bx>>7 (0..3)
// launch_bounds(256,2): grid is exactly 2 wg/CU; asking for 3 waves/EU only
// squeezed the register allocator (VGPR cap ~170) -> scratch spill -> the
// ~190 MB/dispatch write storm seen in R2-R4. 2 waves/EU doubles the budget.
__global__ __launch_bounds__(256, 2) void k_attn(const unsigned short* __restrict__ Qh,
                                                 const unsigned short* __restrict__ QhT,
                                                 unsigned short* __restrict__ Opart,
                                                 float* __restrict__ Lpart) {
  __shared__ unsigned short Kt[64 * 64];   // [key][d], 16B chunks XOR-swizzled by row&7
  __shared__ unsigned short Vt[64 * 64];   // [d][key], same swizzle
  __shared__ unsigned short Pb[256 * 64];  // [q_local][key], same swizzle, wave-private rows
  int bx = blockIdx.x;
  int p = bx & 7;
  int u = bx >> 3;
  int qsup = u & 15, ks = u >> 4;
  int t = threadIdx.x;
  int wv = t >> 6, lane = t & 63, g = lane >> 4, ln = lane & 15;
  const unsigned short* Qp = Qh + (size_t)p * L_SEQ * DH;
  const unsigned short* QTp = QhT + (size_t)p * DH * L_SEQ;
  int q0 = qsup * 256;
  int qw = q0 + wv * 64;  // this wave's 64 q-columns

  // Q^T fragments (B operand), cached for the whole loop: 8 x b128
  bf16x8 aQ[4][2];
#pragma unroll
  for (int nt = 0; nt < 4; ++nt)
#pragma unroll
    for (int kc = 0; kc < 2; ++kc)
      aQ[nt][kc] = ld_frag(Qp + (size_t)(qw + nt * 16 + ln) * DH + kc * 32 + g * 8);

  f32x4 oacc[4][4] = {};
  float lacc[4] = {0.f, 0.f, 0.f, 0.f};

  // staging addresses (2 chunks each of Kt, Vt per thread)
  int srow0 = t >> 3, scol0 = t & 7;
  int srow1 = (t + 256) >> 3, scol1 = (t + 256) & 7;
  int sdst0 = srow0 * 64 + ((scol0 ^ (srow0 & 7)) * 8);
  int sdst1 = srow1 * 64 + ((scol1 ^ (srow1 & 7)) * 8);

  ushort8v kreg0, kreg1, vreg0, vreg1;
  {
    int kbase = (ks * NKB) * 64;
    kreg0 = *(const ushort8v*)(Qp + (size_t)(kbase + srow0) * DH + scol0 * 8);
    kreg1 = *(const ushort8v*)(Qp + (size_t)(kbase + srow1) * DH + scol1 * 8);
    vreg0 = *(const ushort8v*)(QTp + (size_t)srow0 * L_SEQ + kbase + scol0 * 8);
    vreg1 = *(const ushort8v*)(QTp + (size_t)srow1 * L_SEQ + kbase + scol1 * 8);
  }

  for (int kb = 0; kb < NKB; ++kb) {
    __syncthreads();  // all waves done reading Kt/Vt of previous kb
    *(ushort8v*)(Kt + sdst0) = kreg0;
    *(ushort8v*)(Kt + sdst1) = kreg1;
    *(ushort8v*)(Vt + sdst0) = vreg0;
    *(ushort8v*)(Vt + sdst1) = vreg1;
    __syncthreads();  // staging visible
    if (kb + 1 < NKB) {
      int kbase = (ks * NKB + kb + 1) * 64;
      kreg0 = *(const ushort8v*)(Qp + (size_t)(kbase + srow0) * DH + scol0 * 8);
      kreg1 = *(const ushort8v*)(Qp + (size_t)(kbase + srow1) * DH + scol1 * 8);
      vreg0 = *(const ushort8v*)(QTp + (size_t)srow0 * L_SEQ + kbase + scol0 * 8);
      vreg1 = *(const ushort8v*)(QTp + (size_t)srow1 * L_SEQ + kbase + scol1 * 8);
    }
    // ---- S^T = K Q^T, one 16-key m-tile at a time ----
#pragma unroll
    for (int mt = 0; mt < 4; ++mt) {
      int krow = mt * 16 + ln;
      bf16x8 aK0 = ld_frag(Kt + krow * 64 + (((0 * 4 + g) ^ (ln & 7)) * 8));
      bf16x8 aK1 = ld_frag(Kt + krow * 64 + (((1 * 4 + g) ^ (ln & 7)) * 8));
      f32x4 s[4] = {};
#pragma unroll
      for (int nt = 0; nt < 4; ++nt) {
        s[nt] = __builtin_amdgcn_mfma_f32_16x16x32_bf16(aK0, aQ[nt][0], s[nt], 0, 0, 0);
        s[nt] = __builtin_amdgcn_mfma_f32_16x16x32_bf16(aK1, aQ[nt][1], s[nt], 0, 0, 0);
      }
      // exp(s/8 - 16), accumulate l, pack P^T tile rows -> Pb[q][key] (b64 writes)
#pragma unroll
      for (int nt = 0; nt < 4; ++nt) {
        float p0 = __expf(fmaf(s[nt][0], 0.125f, -16.0f));
        float p1 = __expf(fmaf(s[nt][1], 0.125f, -16.0f));
        float p2 = __expf(fmaf(s[nt][2], 0.125f, -16.0f));
        float p3 = __expf(fmaf(s[nt][3], 0.125f, -16.0f));
        lacc[nt] += (p0 + p1) + (p2 + p3);
        ushort4v pk = {f2bf(p0), f2bf(p1), f2bf(p2), f2bf(p3)};
        int row = wv * 64 + nt * 16 + ln;
        int addr = row * 64 + (((2 * mt + (g >> 1)) ^ (ln & 7)) * 8) + (g & 1) * 4;
        *(ushort4v*)(Pb + addr) = pk;
      }
    }
    // ---- O += P V ----
#pragma unroll
    for (int kc = 0; kc < 2; ++kc) {
      bf16x8 bV[4];
#pragma unroll
      for (int tn = 0; tn < 4; ++tn)
        bV[tn] = ld_frag(Vt + (tn * 16 + ln) * 64 + (((kc * 4 + g) ^ (ln & 7)) * 8));
#pragma unroll
      for (int mq = 0; mq < 4; ++mq) {
        bf16x8 aP = ld_frag(Pb + (wv * 64 + mq * 16 + ln) * 64 + (((kc * 4 + g) ^ (ln & 7)) * 8));
#pragma unroll
        for (int tn = 0; tn < 4; ++tn)
          oacc[mq][tn] = __builtin_amdgcn_mfma_f32_16x16x32_bf16(aP, bV[tn], oacc[mq][tn], 0, 0, 0);
      }
    }
  }
  // l: reduce over the 4 g-quads
#pragma unroll
  for (int nt = 0; nt < 4; ++nt) {
    lacc[nt] += __shfl_xor(lacc[nt], 16, 64);
    lacc[nt] += __shfl_xor(lacc[nt], 32, 64);
  }
  size_t pq = (size_t)(ks * 8 + p) * L_SEQ;
  if (g == 0) {
#pragma unroll
    for (int nt = 0; nt < 4; ++nt)
      __builtin_nontemporal_store(lacc[nt], &Lpart[pq + qw + nt * 16 + ln]);
  }
  // ---- epilogue: bounce O through Pb (wave-private rows), dense nt stores ----
#pragma unroll
  for (int mq = 0; mq < 4; ++mq) {
#pragma unroll
    for (int r = 0; r < 4; ++r) {
      int row = wv * 64 + mq * 16 + g * 4 + r;   // q_local in [wv*64, wv*64+64)
#pragma unroll
      for (int tn = 0; tn < 4; ++tn) {
        int d = tn * 16 + ln;
        Pb[row * 64 + (((d >> 3) ^ (row & 7)) * 8) + (d & 7)] = f2bf(oacc[mq][tn][r]);
      }
    }
  }
  // no barrier needed: each wave reads back only its own rows
#pragma unroll
  for (int s = 0; s < 8; ++s) {
    int flat = s * 64 + lane;
    int row = wv * 64 + (flat >> 3);
    int c8 = lane & 7;
    ushort8v v = *(const ushort8v*)(Pb + row * 64 + ((c8 ^ (row & 7)) * 8));
    __builtin_nontemporal_store(v, (ushort8v*)(Opart + (pq + q0 + row) * DH + c8 * 8));
  }
}

// ---- 4. FC GEMM (fused ks-merge in A-staging) + bias + residual + LayerNorm ----
#define CP 72
__global__ __launch_bounds__(256) void k_fc(const unsigned short* __restrict__ Opart,
                                            const float* __restrict__ Lpart,
                                            const unsigned short* __restrict__ fcwbf,
                                            const float* __restrict__ qres,
                                            const float* __restrict__ fcb,
                                            const float* __restrict__ lng,
                                            const float* __restrict__ lnb,
                                            float* __restrict__ out) {
  __shared__ unsigned short As[32 * CP];
  __shared__ unsigned short Bs[256 * CP];
  __shared__ float redS[4][32], redQ[4][32], muA[32], rsA[32];
  int bx = blockIdx.x;
  int m0 = bx * 32;
  int b = m0 >> 12, lpart = m0 & 4095;
  int t = threadIdx.x;
  int wv = t >> 6, lane = t & 63, g = lane >> 4, ln = lane & 15;
  f32x4 acc[2][4] = {};
  for (int kb = 0; kb < 4; ++kb) {   // kb == head index for A-staging
    {
      int row = t >> 3, c0 = (t & 7) * 8;
      int q = lpart + row;
      int p = b * 4 + kb;
      float lsum = __builtin_nontemporal_load(&Lpart[(size_t)(0 * 8 + p) * L_SEQ + q]) +
                   __builtin_nontemporal_load(&Lpart[(size_t)(1 * 8 + p) * L_SEQ + q]) +
                   __builtin_nontemporal_load(&Lpart[(size_t)(2 * 8 + p) * L_SEQ + q]) +
                   __builtin_nontemporal_load(&Lpart[(size_t)(3 * 8 + p) * L_SEQ + q]);
      float inv = 1.0f / lsum;
      float a8[8] = {0.f, 0.f, 0.f, 0.f, 0.f, 0.f, 0.f, 0.f};
#pragma unroll
      for (int ksp = 0; ksp < 4; ++ksp) {
        ushort8v v = __builtin_nontemporal_load(
            (const ushort8v*)(Opart + ((size_t)(ksp * 8 + p) * L_SEQ + q) * DH + c0));
#pragma unroll
        for (int j = 0; j < 8; ++j) a8[j] += bf2f(v[j]);
      }
      ushort8v o;
#pragma unroll
      for (int j = 0; j < 8; ++j) o[j] = f2bf(a8[j] * inv);
      *(ushort8v*)(As + row * CP + c0) = o;
    }
#pragma unroll
    for (int it = 0; it < 8; ++it) {
      int idx = t + it * 256;
      int row = idx >> 3, c0 = (idx & 7) * 8;
      *(ushort8v*)(Bs + row * CP + c0) =
          *(const ushort8v*)(fcwbf + (size_t)row * 256 + kb * 64 + c0);
    }
    __syncthreads();
#pragma unroll
    for (int kc = 0; kc < 2; ++kc) {
      bf16x8 a[2], bb[4];
#pragma unroll
      for (int mt = 0; mt < 2; ++mt) a[mt] = ld_frag(As + (mt * 16 + ln) * CP + kc * 32 + g * 8);
#pragma unroll
      for (int tn = 0; tn < 4; ++tn) bb[tn] = ld_frag(Bs + (wv * 64 + tn * 16 + ln) * CP + kc * 32 + g * 8);
#pragma unroll
      for (int mt = 0; mt < 2; ++mt)
#pragma unroll
        for (int tn = 0; tn < 4; ++tn)
          acc[mt][tn] = __builtin_amdgcn_mfma_f32_16x16x32_bf16(a[mt], bb[tn], acc[mt][tn], 0, 0, 0);
    }
    __syncthreads();
  }
  float fb[4], lg[4], lb[4];
#pragma unroll
  for (int tn = 0; tn < 4; ++tn) {
    int o = wv * 64 + tn * 16 + ln;
    fb[tn] = fcb[o]; lg[tn] = lng[o]; lb[tn] = lnb[o];
  }
#pragma unroll
  for (int mt = 0; mt < 2; ++mt) {
    float ps[4] = {0.f, 0.f, 0.f, 0.f}, pq2[4] = {0.f, 0.f, 0.f, 0.f};
#pragma unroll
    for (int tn = 0; tn < 4; ++tn) {
      int o = wv * 64 + tn * 16 + ln;
      float4 res = *(const float4*)(qres + ((size_t)(b * 256 + o)) * 4096 + lpart + mt * 16 + g * 4);
      float rv[4] = {res.x, res.y, res.z, res.w};
#pragma unroll
      for (int r = 0; r < 4; ++r) {
        float v = acc[mt][tn][r] + fb[tn] + rv[r];
        acc[mt][tn][r] = v;
        ps[r] += v;
        pq2[r] += v * v;
      }
    }
#pragma unroll
    for (int r = 0; r < 4; ++r) {
      float s = ps[r], q2 = pq2[r];
#pragma unroll
      for (int off = 1; off < 16; off <<= 1) {
        s += __shfl_xor(s, off, 64);
        q2 += __shfl_xor(q2, off, 64);
      }
      if (ln == 0) {
        int row = mt * 16 + g * 4 + r;
        redS[wv][row] = s;
        redQ[wv][row] = q2;
      }
    }
  }
  __syncthreads();
  if (t < 32) {
    float s = redS[0][t] + redS[1][t] + redS[2][t] + redS[3][t];
    float q2 = redQ[0][t] + redQ[1][t] + redQ[2][t] + redQ[3][t];
    float mu = s * (1.f / 256.f);
    float var = q2 * (1.f / 256.f) - mu * mu;
    muA[t] = mu;
    rsA[t] = rsqrtf(var + 1e-5f);
  }
  __syncthreads();
#pragma unroll
  for (int mt = 0; mt < 2; ++mt) {
#pragma unroll
    for (int r = 0; r < 4; ++r) {
      int row = mt * 16 + g * 4 + r;
      float mu = muA[row], rs = rsA[row];
#pragma unroll
      for (int tn = 0; tn < 4; ++tn) {
        int o = wv * 64 + tn * 16 + ln;
        out[(size_t)(m0 + row) * 256 + o] = (acc[mt][tn][r] - mu) * rs * lg[tn] + lb[tn];
      }
    }
  }
}

extern "C" void kernel_launch(void* const* d_in, const int* in_sizes, int n_in,
                              void* d_out, int out_size, void* d_ws, size_t ws_size,
                              hipStream_t stream) {
  const float* q = (const float*)d_in[0];
  const float* w_qkv = (const float*)d_in[1];
  const float* fc_w = (const float*)d_in[2];
  const float* fc_b = (const float*)d_in[3];
  const float* ln_g = (const float*)d_in[4];
  const float* ln_b = (const float*)d_in[5];
  float* out = (float*)d_out;

  unsigned short* wbf = (unsigned short*)d_ws;   // 65536
  unsigned short* fcwbf = wbf + 65536;           // 65536
  unsigned short* xbf = fcwbf + 65536;           // 8192*256
  unsigned short* Qh = xbf + 2097152;            // [p][l][d]
  unsigned short* QhT = Qh + 2097152;            // [p][d][l]
  unsigned short* Opart = QhT + 2097152;         // [ks][p][q][d] bf16, 4*2M
  float* Lpart = (float*)(Opart + 8388608);      // [ks][p][q] fp32
  // total ws use: ~30.1 MB

  k_transpose<<<dim3(576), dim3(256), 0, stream>>>(q, xbf, w_qkv, fc_w, wbf, fcwbf);
  k_qkv<<<dim3(512), dim3(256), 0, stream>>>(xbf, wbf, Qh, QhT);
  k_attn<<<dim3(512), dim3(256), 0, stream>>>(Qh, QhT, Opart, Lpart);
  k_fc<<<dim3(256), dim3(256), 0, stream>>>(Opart, Lpart, fcwbf, q, fc_b, ln_g, ln_b, out);
}